// Round 12
// baseline (170.987 us; speedup 1.0000x reference)
//
#include <hip/hip_runtime.h>
#include <math.h>

#define N_NODES 50000
#define N_EDGES 800000
#define D_IN    64
#define H_HID   16
#define C_OUT   40

#define BSH     8                                  // 256 nodes per bucket
#define BNODES  256
#define BMASK   255
#define NBUCK   ((N_NODES + BNODES - 1) / BNODES)  // 196
#define NBUCKP  200                                // padded stride for part arrays
#define NBLK    500                                // edge slabs
#define EPB     (N_EDGES / NBLK)                   // 1600 exact, 16B-aligned
#define EPB4    (EPB / 4)                          // 400 int4s per slab

// ---- pass A: per-(block,bucket) histograms, LDS only; part[block][bucket] ----
__global__ void bucket_count(const int* __restrict__ src, const int* __restrict__ dst,
                             int* __restrict__ partS, int* __restrict__ partD,
                             unsigned int* __restrict__ done) {
    if (blockIdx.x == 0 && threadIdx.x == 0) *done = 0;   // reset last-block counter each launch
    __shared__ int hS[NBUCK], hD[NBUCK];
    for (int i = threadIdx.x; i < NBUCK; i += blockDim.x) { hS[i] = 0; hD[i] = 0; }
    __syncthreads();
    const int4* s4 = (const int4*)(src + blockIdx.x * EPB);
    const int4* d4 = (const int4*)(dst + blockIdx.x * EPB);
    for (int k = threadIdx.x; k < EPB4; k += blockDim.x) {
        int4 s = s4[k], d = d4[k];
        atomicAdd(&hS[s.x >> BSH], 1); atomicAdd(&hS[s.y >> BSH], 1);
        atomicAdd(&hS[s.z >> BSH], 1); atomicAdd(&hS[s.w >> BSH], 1);
        atomicAdd(&hD[d.x >> BSH], 1); atomicAdd(&hD[d.y >> BSH], 1);
        atomicAdd(&hD[d.z >> BSH], 1); atomicAdd(&hD[d.w >> BSH], 1);
    }
    __syncthreads();
    for (int i = threadIdx.x; i < NBUCK; i += blockDim.x) {
        partS[blockIdx.x * NBUCKP + i] = hS[i];
        partD[blockIdx.x * NBUCKP + i] = hD[i];
    }
}

// ---- prefix over blocks per bucket; LAST block also scans bucket totals -> base ----
__global__ void bucket_base_scan(int* __restrict__ partS, int* __restrict__ partD,
                                 int* __restrict__ totS, int* __restrict__ totD,
                                 int* __restrict__ baseS, int* __restrict__ baseD,
                                 unsigned int* __restrict__ done) {
    int* part = blockIdx.y ? partD : partS;
    int* tot  = blockIdx.y ? totD  : totS;
    int b = blockIdx.x;
    __shared__ int s[512];
    __shared__ unsigned int rank;
    int k = threadIdx.x;
    int v = (k < NBLK) ? part[k * NBUCKP + b] : 0;
    s[k] = v;
    __syncthreads();
    for (int off = 1; off < 512; off <<= 1) {
        int t = (k >= off) ? s[k - off] : 0;
        __syncthreads();
        s[k] += t;
        __syncthreads();
    }
    if (k < NBLK) part[k * NBUCKP + b] = s[k] - v;   // exclusive within bucket
    if (k == 511) tot[b] = s[511];
    // last-block-done: final exclusive scans of totS/totD -> baseS/baseD
    __threadfence();
    __syncthreads();
    if (k == 0) rank = atomicAdd(done, 1u);
    __syncthreads();
    if (rank == 2 * NBUCK - 1) {
        for (int which = 0; which < 2; ++which) {
            const int* t = which ? totD : totS;
            int* base = which ? baseD : baseS;
            int vv = (k < NBUCK) ? t[k] : 0;
            __syncthreads();
            s[k] = vv;
            __syncthreads();
            for (int off = 1; off < 512; off <<= 1) {
                int tt = (k >= off) ? s[k - off] : 0;
                __syncthreads();
                s[k] += tt;
                __syncthreads();
            }
            if (k < NBUCK) base[k] = s[k] - vv;
            if (k == NBUCK - 1) base[NBUCK] = s[k];   // == N_EDGES
            __syncthreads();
        }
    }
}

// ---- pass B: scatter edges into bucket-grouped arrays; cursors = 2 coalesced loads ----
__global__ void bucket_scatter(const int* __restrict__ src, const int* __restrict__ dst,
                               const int* __restrict__ partS, const int* __restrict__ partD,
                               const int* __restrict__ baseS, const int* __restrict__ baseD,
                               unsigned int* __restrict__ packedD,
                               unsigned char* __restrict__ srcloc) {
    __shared__ int cS[NBUCK], cD[NBUCK];
    int blk = blockIdx.x;
    for (int b = threadIdx.x; b < NBUCK; b += blockDim.x) {
        cS[b] = baseS[b] + partS[blk * NBUCKP + b];
        cD[b] = baseD[b] + partD[blk * NBUCKP + b];
    }
    __syncthreads();
    const int4* s4 = (const int4*)(src + blk * EPB);
    const int4* d4 = (const int4*)(dst + blk * EPB);
    for (int k = threadIdx.x; k < EPB4; k += blockDim.x) {
        int4 sv = s4[k], dv = d4[k];
        int ss[4] = { sv.x, sv.y, sv.z, sv.w };
        int dd[4] = { dv.x, dv.y, dv.z, dv.w };
        #pragma unroll
        for (int u = 0; u < 4; ++u) {
            int s = ss[u], d = dd[u];
            int pD = atomicAdd(&cD[d >> BSH], 1);
            packedD[pD] = (unsigned)s | ((unsigned)(d & BMASK) << 16);
            int pS = atomicAdd(&cS[s >> BSH], 1);
            srcloc[pS] = (unsigned char)(s & BMASK);
        }
    }
}

// ---- per-bucket counting sort -> per-node CSR (col, rowptr) + src-degree -> dinv ----
__global__ void csr_build(const unsigned int* __restrict__ packedD, const int* __restrict__ baseD,
                          const unsigned char* __restrict__ srcloc, const int* __restrict__ baseS,
                          int* __restrict__ col, int* __restrict__ rowptr,
                          float* __restrict__ dinv) {
    __shared__ int hist[BNODES], scanv[BNODES], cur[BNODES], shist[BNODES];
    int tid = threadIdx.x;
    if (tid < BNODES) { hist[tid] = 0; shist[tid] = 0; }
    __syncthreads();
    int bb = blockIdx.x;
    int begD = baseD[bb], endD = baseD[bb + 1];
    for (int j = begD + tid; j < endD; j += blockDim.x)
        atomicAdd(&hist[(packedD[j] >> 16) & BMASK], 1);
    int begS = baseS[bb], endS = baseS[bb + 1];
    for (int j = begS + tid; j < endS; j += blockDim.x)
        atomicAdd(&shist[srcloc[j]], 1);
    __syncthreads();
    if (tid == 0) {
        int acc = 0;
        for (int i = 0; i < BNODES; ++i) { scanv[i] = acc; acc += hist[i]; }
    }
    __syncthreads();
    if (tid < BNODES) {
        cur[tid] = scanv[tid];
        int node = bb * BNODES + tid;
        if (node < N_NODES) {
            rowptr[node] = begD + scanv[tid];
            int d = shist[tid];
            dinv[node] = (d > 0) ? rsqrtf((float)d) : 0.0f;
        }
    }
    if (bb == NBUCK - 1 && tid == 0) rowptr[N_NODES] = endD;   // == N_EDGES
    __syncthreads();
    for (int j = begD + tid; j < endD; j += blockDim.x) {
        unsigned rec = packedD[j];
        int dl = (rec >> 16) & BMASK;
        int pos = atomicAdd(&cur[dl], 1);
        col[begD + pos] = (int)(rec & 0xFFFF);   // global src id (fits 16b: N<65536)
    }
}

// ---- xw0 = x@W1[0]; sxw1 = dinv * (x@W1[1]) ----
__global__ void xw_kernel(const float* __restrict__ x, const float* __restrict__ W1,
                          const float* __restrict__ dinv,
                          float* __restrict__ xw0, float* __restrict__ sxw1) {
    __shared__ float sW[2 * D_IN * H_HID];   // 8 KB
    __shared__ float sx[16 * 65];
    for (int i = threadIdx.x; i < 2 * D_IN * H_HID; i += 256) sW[i] = W1[i];
    int nbase = blockIdx.x * 16;
    for (int i = threadIdx.x; i < 16 * D_IN; i += 256) {
        int r = i >> 6, c = i & 63;
        sx[r * 65 + c] = x[(size_t)(nbase + r) * D_IN + c];
    }
    __syncthreads();
    int nl = threadIdx.x >> 4, f = threadIdx.x & 15;
    int node = nbase + nl;                    // N = 3125*16 exactly
    float a0 = 0.f, a1 = 0.f;
    #pragma unroll
    for (int d = 0; d < D_IN; ++d) {
        float xv = sx[nl * 65 + d];
        a0 += xv * sW[d * H_HID + f];
        a1 += xv * sW[D_IN * H_HID + d * H_HID + f];
    }
    int t = node * H_HID + f;
    xw0[t]  = a0;
    sxw1[t] = dinv[node] * a1;
}

// ---- layer-1 gather: 8 lanes/node = 2 half-groups x float4; split-K over edges ----
__global__ void gather1(const int* __restrict__ rowptr, const int* __restrict__ col,
                        const float* __restrict__ dinv, const float* __restrict__ sxw1,
                        const float* __restrict__ xw0, const float* __restrict__ b1,
                        float* __restrict__ h, float* __restrict__ sh) {
    int grp  = threadIdx.x >> 2;              // 128 groups per 512-thread block
    int f4   = threadIdx.x & 3;
    int half = grp & 1;
    int node = blockIdx.x * 64 + (grp >> 1);
    if (node >= N_NODES) return;
    int beg = rowptr[node], end = rowptr[node + 1];
    const float4* sx4 = (const float4*)sxw1;
    float4 a = make_float4(0.f, 0.f, 0.f, 0.f);
    int j = beg + half * 8;
    for (; j + 8 <= end; j += 16) {           // alternate 8-edge batches per half
        int c0 = col[j],     c1 = col[j + 1], c2 = col[j + 2], c3 = col[j + 3];
        int c4 = col[j + 4], c5 = col[j + 5], c6 = col[j + 6], c7 = col[j + 7];
        float4 v0 = sx4[c0 * 4 + f4], v1 = sx4[c1 * 4 + f4];
        float4 v2 = sx4[c2 * 4 + f4], v3 = sx4[c3 * 4 + f4];
        float4 v4 = sx4[c4 * 4 + f4], v5 = sx4[c5 * 4 + f4];
        float4 v6 = sx4[c6 * 4 + f4], v7 = sx4[c7 * 4 + f4];
        a.x += ((v0.x + v1.x) + (v2.x + v3.x)) + ((v4.x + v5.x) + (v6.x + v7.x));
        a.y += ((v0.y + v1.y) + (v2.y + v3.y)) + ((v4.y + v5.y) + (v6.y + v7.y));
        a.z += ((v0.z + v1.z) + (v2.z + v3.z)) + ((v4.z + v5.z) + (v6.z + v7.z));
        a.w += ((v0.w + v1.w) + (v2.w + v3.w)) + ((v4.w + v5.w) + (v6.w + v7.w));
    }
    for (; j < end; ++j) {                    // tail batch: only its parity enters
        float4 v = sx4[col[j] * 4 + f4];
        a.x += v.x; a.y += v.y; a.z += v.z; a.w += v.w;
    }
    a.x += __shfl_xor(a.x, 4);
    a.y += __shfl_xor(a.y, 4);
    a.z += __shfl_xor(a.z, 4);
    a.w += __shfl_xor(a.w, 4);
    if (!half) {
        float di = dinv[node];
        float4 x0 = ((const float4*)xw0)[node * 4 + f4];
        float4 bb = ((const float4*)b1)[f4];
        float vx = fmaxf(x0.x - di * a.x + bb.x, 0.f);
        float vy = fmaxf(x0.y - di * a.y + bb.y, 0.f);
        float vz = fmaxf(x0.z - di * a.z + bb.z, 0.f);
        float vw = fmaxf(x0.w - di * a.w + bb.w, 0.f);
        ((float4*)h)[node * 4 + f4]  = make_float4(vx, vy, vz, vw);
        ((float4*)sh)[node * 4 + f4] = make_float4(di * vx, di * vy, di * vz, di * vw);
    }
}

// ---- layer-2 gather FUSED with dual matmul + log_softmax (8-lane epilogue) ----
#define HROW 20   // padded row stride (floats)
__global__ void gather2_out(const int* __restrict__ rowptr, const int* __restrict__ col,
                            const float* __restrict__ dinv, const float* __restrict__ sh,
                            const float* __restrict__ h, const float* __restrict__ W2,
                            const float* __restrict__ b2, float* __restrict__ out) {
    __shared__ float sW0[H_HID * C_OUT], sW1[H_HID * C_OUT], sb[C_OUT];
    __shared__ float hrow[64][HROW];    // 5 KB
    __shared__ float trow[64][HROW];    // 5 KB
    for (int i = threadIdx.x; i < H_HID * C_OUT; i += 512) {
        sW0[i] = W2[i];
        sW1[i] = W2[H_HID * C_OUT + i];
    }
    if (threadIdx.x < C_OUT) sb[threadIdx.x] = b2[threadIdx.x];

    int grp  = threadIdx.x >> 2;
    int f4   = threadIdx.x & 3;
    int half = grp & 1;
    int nl   = grp >> 1;                 // 0..63 node-local
    int node = blockIdx.x * 64 + nl;
    bool active = node < N_NODES;
    int beg = 0, end = 0;
    float di = 0.f;
    if (active) { beg = rowptr[node]; end = rowptr[node + 1]; di = dinv[node]; }
    const float4* sh4 = (const float4*)sh;
    float4 a = make_float4(0.f, 0.f, 0.f, 0.f);
    int j = beg + half * 8;
    for (; j + 8 <= end; j += 16) {
        int c0 = col[j],     c1 = col[j + 1], c2 = col[j + 2], c3 = col[j + 3];
        int c4 = col[j + 4], c5 = col[j + 5], c6 = col[j + 6], c7 = col[j + 7];
        float4 v0 = sh4[c0 * 4 + f4], v1 = sh4[c1 * 4 + f4];
        float4 v2 = sh4[c2 * 4 + f4], v3 = sh4[c3 * 4 + f4];
        float4 v4 = sh4[c4 * 4 + f4], v5 = sh4[c5 * 4 + f4];
        float4 v6 = sh4[c6 * 4 + f4], v7 = sh4[c7 * 4 + f4];
        a.x += ((v0.x + v1.x) + (v2.x + v3.x)) + ((v4.x + v5.x) + (v6.x + v7.x));
        a.y += ((v0.y + v1.y) + (v2.y + v3.y)) + ((v4.y + v5.y) + (v6.y + v7.y));
        a.z += ((v0.z + v1.z) + (v2.z + v3.z)) + ((v4.z + v5.z) + (v6.z + v7.z));
        a.w += ((v0.w + v1.w) + (v2.w + v3.w)) + ((v4.w + v5.w) + (v6.w + v7.w));
    }
    for (; j < end; ++j) {
        float4 v = sh4[col[j] * 4 + f4];
        a.x += v.x; a.y += v.y; a.z += v.z; a.w += v.w;
    }
    a.x += __shfl_xor(a.x, 4);
    a.y += __shfl_xor(a.y, 4);
    a.z += __shfl_xor(a.z, 4);
    a.w += __shfl_xor(a.w, 4);
    if (!half) {
        float4 hp = make_float4(0.f, 0.f, 0.f, 0.f);
        if (active) hp = ((const float4*)h)[node * 4 + f4];
        hrow[nl][4 * f4 + 0] = hp.x;
        hrow[nl][4 * f4 + 1] = hp.y;
        hrow[nl][4 * f4 + 2] = hp.z;
        hrow[nl][4 * f4 + 3] = hp.w;
        trow[nl][4 * f4 + 0] = -di * a.x;
        trow[nl][4 * f4 + 1] = -di * a.y;
        trow[nl][4 * f4 + 2] = -di * a.z;
        trow[nl][4 * f4 + 3] = -di * a.w;
    }
    __syncthreads();

    int l8 = threadIdx.x & 7;            // 8 lanes per node, 5 classes each
    float hv[H_HID], tv[H_HID];
    #pragma unroll
    for (int ff = 0; ff < H_HID; ++ff) {
        hv[ff] = hrow[nl][ff];
        tv[ff] = trow[nl][ff];
    }
    float o[5];
    float mx = -1e30f;
    #pragma unroll
    for (int i = 0; i < 5; ++i) {
        int c = l8 * 5 + i;
        float aa = sb[c];
        #pragma unroll
        for (int ff = 0; ff < H_HID; ++ff)
            aa += hv[ff] * sW0[ff * C_OUT + c] + tv[ff] * sW1[ff * C_OUT + c];
        o[i] = aa;
        mx = fmaxf(mx, aa);
    }
    mx = fmaxf(mx, __shfl_xor(mx, 1));
    mx = fmaxf(mx, __shfl_xor(mx, 2));
    mx = fmaxf(mx, __shfl_xor(mx, 4));
    float sum = 0.f;
    #pragma unroll
    for (int i = 0; i < 5; ++i) sum += expf(o[i] - mx);
    sum += __shfl_xor(sum, 1);
    sum += __shfl_xor(sum, 2);
    sum += __shfl_xor(sum, 4);
    float lse = mx + logf(sum);
    if (active) {
        float* op = out + (size_t)node * C_OUT + l8 * 5;
        #pragma unroll
        for (int i = 0; i < 5; ++i) op[i] = o[i] - lse;
    }
}

extern "C" void kernel_launch(void* const* d_in, const int* in_sizes, int n_in,
                              void* d_out, int out_size, void* d_ws, size_t ws_size,
                              hipStream_t stream) {
    const float* x   = (const float*)d_in[0];
    const int*   ei  = (const int*)d_in[1];
    const float* W1  = (const float*)d_in[2];
    const float* b1  = (const float*)d_in[3];
    const float* W2  = (const float*)d_in[4];
    const float* b2  = (const float*)d_in[5];
    float* out = (float*)d_out;

    const int* src = ei;            // edge_index[0]
    const int* dst = ei + N_EDGES;  // edge_index[1]

    // workspace layout
    int* partS = (int*)d_ws;                                      // NBLK*NBUCKP
    int* partD = partS + NBLK * NBUCKP;                           // NBLK*NBUCKP
    int* baseS = partD + NBLK * NBUCKP;                           // NBUCK+1 (pad 512)
    int* baseD = baseS + 512;                                     // NBUCK+1 (pad 512)
    int* totS  = baseD + 512;                                     // NBUCK (pad 512)
    int* totD  = totS + 512;                                      // NBUCK (pad 512)
    unsigned int* done = (unsigned int*)(totD + 512);             // 1 (pad 4)
    unsigned int*  packedD = (unsigned int*)(done + 4);           // E
    unsigned char* srcloc  = (unsigned char*)(packedD + N_EDGES); // E bytes
    int*   col    = (int*)(srcloc + N_EDGES);                     // E
    int*   rowptr = col + N_EDGES;                                // N+1 (pad)
    float* dinv   = (float*)(rowptr + N_NODES + 8);               // N
    float* xw0    = dinv + N_NODES;                               // N*16
    float* sxw1   = xw0  + (size_t)N_NODES * H_HID;               // N*16
    float* h      = sxw1 + (size_t)N_NODES * H_HID;               // N*16
    float* sh     = h    + (size_t)N_NODES * H_HID;               // N*16

    bucket_count    <<<NBLK, 256, 0, stream>>>(src, dst, partS, partD, done);
    bucket_base_scan<<<dim3(NBUCK, 2), 512, 0, stream>>>(partS, partD, totS, totD, baseS, baseD, done);
    bucket_scatter  <<<NBLK, 256, 0, stream>>>(src, dst, partS, partD, baseS, baseD, packedD, srcloc);
    csr_build       <<<NBUCK, 512, 0, stream>>>(packedD, baseD, srcloc, baseS, col, rowptr, dinv);
    xw_kernel       <<<N_NODES / 16, 256, 0, stream>>>(x, W1, dinv, xw0, sxw1);
    gather1         <<<(N_NODES + 63) / 64, 512, 0, stream>>>(rowptr, col, dinv, sxw1, xw0, b1, h, sh);
    gather2_out     <<<(N_NODES + 63) / 64, 512, 0, stream>>>(rowptr, col, dinv, sh, h, W2, b2, out);
}

// Round 13
// 94.045 us; speedup vs baseline: 1.8181x; 1.8181x over previous
//
#include <hip/hip_runtime.h>
#include <math.h>

#define N_NODES 50000
#define N_EDGES 800000
#define D_IN    64
#define H_HID   16
#define C_OUT   40

#define BSH     8                                  // 256 nodes per bucket
#define BNODES  256
#define BMASK   255
#define NBUCK   ((N_NODES + BNODES - 1) / BNODES)  // 196
#define NBUCKP  200                                // padded stride for part arrays
#define NBLK    500                                // edge slabs
#define EPB     (N_EDGES / NBLK)                   // 1600 exact, 16B-aligned
#define EPB4    (EPB / 4)                          // 400 int4s per slab

// ---- pass A: per-(block,bucket) histograms, LDS only; part[block][bucket] ----
__global__ void bucket_count(const int* __restrict__ src, const int* __restrict__ dst,
                             int* __restrict__ partS, int* __restrict__ partD) {
    __shared__ int hS[NBUCK], hD[NBUCK];
    for (int i = threadIdx.x; i < NBUCK; i += blockDim.x) { hS[i] = 0; hD[i] = 0; }
    __syncthreads();
    const int4* s4 = (const int4*)(src + blockIdx.x * EPB);
    const int4* d4 = (const int4*)(dst + blockIdx.x * EPB);
    for (int k = threadIdx.x; k < EPB4; k += blockDim.x) {
        int4 s = s4[k], d = d4[k];
        atomicAdd(&hS[s.x >> BSH], 1); atomicAdd(&hS[s.y >> BSH], 1);
        atomicAdd(&hS[s.z >> BSH], 1); atomicAdd(&hS[s.w >> BSH], 1);
        atomicAdd(&hD[d.x >> BSH], 1); atomicAdd(&hD[d.y >> BSH], 1);
        atomicAdd(&hD[d.z >> BSH], 1); atomicAdd(&hD[d.w >> BSH], 1);
    }
    __syncthreads();
    for (int i = threadIdx.x; i < NBUCK; i += blockDim.x) {
        partS[blockIdx.x * NBUCKP + i] = hS[i];
        partD[blockIdx.x * NBUCKP + i] = hD[i];
    }
}

// ---- prefix over blocks, one block per (bucket, S/D): part[k][b] <- sum_{k'<k} ----
__global__ void bucket_base_scan(int* __restrict__ partS, int* __restrict__ partD,
                                 int* __restrict__ totS, int* __restrict__ totD) {
    int* part = blockIdx.y ? partD : partS;
    int* tot  = blockIdx.y ? totD  : totS;
    int b = blockIdx.x;
    __shared__ int s[512];
    int k = threadIdx.x;
    int v = (k < NBLK) ? part[k * NBUCKP + b] : 0;
    s[k] = v;
    __syncthreads();
    for (int off = 1; off < 512; off <<= 1) {
        int t = (k >= off) ? s[k - off] : 0;
        __syncthreads();
        s[k] += t;
        __syncthreads();
    }
    if (k < NBLK) part[k * NBUCKP + b] = s[k] - v;   // exclusive within bucket
    if (k == 511) tot[b] = s[511];
}

// ---- exclusive scan of bucket totals -> base ----
__global__ void bucket_base_final(const int* __restrict__ totS, const int* __restrict__ totD,
                                  int* __restrict__ baseS, int* __restrict__ baseD) {
    const int* tot = blockIdx.x ? totD : totS;
    int* base = blockIdx.x ? baseD : baseS;
    __shared__ int s[512];
    int k = threadIdx.x;
    int v = (k < NBUCK) ? tot[k] : 0;
    s[k] = v;
    __syncthreads();
    for (int off = 1; off < 512; off <<= 1) {
        int t = (k >= off) ? s[k - off] : 0;
        __syncthreads();
        s[k] += t;
        __syncthreads();
    }
    if (k < NBUCK) base[k] = s[k] - v;
    if (k == NBUCK - 1) base[NBUCK] = s[k];   // total == N_EDGES
}

// ---- pass B: scatter edges into bucket-grouped arrays; cursors = 2 coalesced loads ----
__global__ void bucket_scatter(const int* __restrict__ src, const int* __restrict__ dst,
                               const int* __restrict__ partS, const int* __restrict__ partD,
                               const int* __restrict__ baseS, const int* __restrict__ baseD,
                               unsigned int* __restrict__ packedD,
                               unsigned char* __restrict__ srcloc) {
    __shared__ int cS[NBUCK], cD[NBUCK];
    int blk = blockIdx.x;
    for (int b = threadIdx.x; b < NBUCK; b += blockDim.x) {
        cS[b] = baseS[b] + partS[blk * NBUCKP + b];
        cD[b] = baseD[b] + partD[blk * NBUCKP + b];
    }
    __syncthreads();
    const int4* s4 = (const int4*)(src + blk * EPB);
    const int4* d4 = (const int4*)(dst + blk * EPB);
    for (int k = threadIdx.x; k < EPB4; k += blockDim.x) {
        int4 sv = s4[k], dv = d4[k];
        int ss[4] = { sv.x, sv.y, sv.z, sv.w };
        int dd[4] = { dv.x, dv.y, dv.z, dv.w };
        #pragma unroll
        for (int u = 0; u < 4; ++u) {
            int s = ss[u], d = dd[u];
            int pD = atomicAdd(&cD[d >> BSH], 1);
            packedD[pD] = (unsigned)s | ((unsigned)(d & BMASK) << 16);
            int pS = atomicAdd(&cS[s >> BSH], 1);
            srcloc[pS] = (unsigned char)(s & BMASK);
        }
    }
}

// ---- per-bucket counting sort -> per-node CSR (col, rowptr) + src-degree -> dinv ----
__global__ void csr_build(const unsigned int* __restrict__ packedD, const int* __restrict__ baseD,
                          const unsigned char* __restrict__ srcloc, const int* __restrict__ baseS,
                          int* __restrict__ col, int* __restrict__ rowptr,
                          float* __restrict__ dinv) {
    __shared__ int hist[BNODES], scanv[BNODES], cur[BNODES], shist[BNODES];
    int tid = threadIdx.x;
    if (tid < BNODES) { hist[tid] = 0; shist[tid] = 0; }
    __syncthreads();
    int bb = blockIdx.x;
    int begD = baseD[bb], endD = baseD[bb + 1];
    for (int j = begD + tid; j < endD; j += blockDim.x)
        atomicAdd(&hist[(packedD[j] >> 16) & BMASK], 1);
    int begS = baseS[bb], endS = baseS[bb + 1];
    for (int j = begS + tid; j < endS; j += blockDim.x)
        atomicAdd(&shist[srcloc[j]], 1);
    __syncthreads();
    if (tid == 0) {
        int acc = 0;
        for (int i = 0; i < BNODES; ++i) { scanv[i] = acc; acc += hist[i]; }
    }
    __syncthreads();
    if (tid < BNODES) {
        cur[tid] = scanv[tid];
        int node = bb * BNODES + tid;
        if (node < N_NODES) {
            rowptr[node] = begD + scanv[tid];
            int d = shist[tid];
            dinv[node] = (d > 0) ? rsqrtf((float)d) : 0.0f;
        }
    }
    if (bb == NBUCK - 1 && tid == 0) rowptr[N_NODES] = endD;   // == N_EDGES
    __syncthreads();
    for (int j = begD + tid; j < endD; j += blockDim.x) {
        unsigned rec = packedD[j];
        int dl = (rec >> 16) & BMASK;
        int pos = atomicAdd(&cur[dl], 1);
        col[begD + pos] = (int)(rec & 0xFFFF);   // global src id (fits 16b: N<65536)
    }
}

// ---- xw0 = x@W1[0]; sxw1 = dinv * (x@W1[1]) ----
__global__ void xw_kernel(const float* __restrict__ x, const float* __restrict__ W1,
                          const float* __restrict__ dinv,
                          float* __restrict__ xw0, float* __restrict__ sxw1) {
    __shared__ float sW[2 * D_IN * H_HID];   // 8 KB
    __shared__ float sx[16 * 65];
    for (int i = threadIdx.x; i < 2 * D_IN * H_HID; i += 256) sW[i] = W1[i];
    int nbase = blockIdx.x * 16;
    for (int i = threadIdx.x; i < 16 * D_IN; i += 256) {
        int r = i >> 6, c = i & 63;
        sx[r * 65 + c] = x[(size_t)(nbase + r) * D_IN + c];
    }
    __syncthreads();
    int nl = threadIdx.x >> 4, f = threadIdx.x & 15;
    int node = nbase + nl;                    // N = 3125*16 exactly
    float a0 = 0.f, a1 = 0.f;
    #pragma unroll
    for (int d = 0; d < D_IN; ++d) {
        float xv = sx[nl * 65 + d];
        a0 += xv * sW[d * H_HID + f];
        a1 += xv * sW[D_IN * H_HID + d * H_HID + f];
    }
    int t = node * H_HID + f;
    xw0[t]  = a0;
    sxw1[t] = dinv[node] * a1;
}

// ---- layer-1 gather: 8 lanes/node = 2 half-groups x float4; split-K over edges ----
__global__ void gather1(const int* __restrict__ rowptr, const int* __restrict__ col,
                        const float* __restrict__ dinv, const float* __restrict__ sxw1,
                        const float* __restrict__ xw0, const float* __restrict__ b1,
                        float* __restrict__ h, float* __restrict__ sh) {
    int grp  = threadIdx.x >> 2;              // 128 groups per 512-thread block
    int f4   = threadIdx.x & 3;
    int half = grp & 1;
    int node = blockIdx.x * 64 + (grp >> 1);
    if (node >= N_NODES) return;
    int beg = rowptr[node], end = rowptr[node + 1];
    const float4* sx4 = (const float4*)sxw1;
    float4 a = make_float4(0.f, 0.f, 0.f, 0.f);
    int j = beg + half * 8;
    for (; j + 8 <= end; j += 16) {           // alternate 8-edge batches per half
        int c0 = col[j],     c1 = col[j + 1], c2 = col[j + 2], c3 = col[j + 3];
        int c4 = col[j + 4], c5 = col[j + 5], c6 = col[j + 6], c7 = col[j + 7];
        float4 v0 = sx4[c0 * 4 + f4], v1 = sx4[c1 * 4 + f4];
        float4 v2 = sx4[c2 * 4 + f4], v3 = sx4[c3 * 4 + f4];
        float4 v4 = sx4[c4 * 4 + f4], v5 = sx4[c5 * 4 + f4];
        float4 v6 = sx4[c6 * 4 + f4], v7 = sx4[c7 * 4 + f4];
        a.x += ((v0.x + v1.x) + (v2.x + v3.x)) + ((v4.x + v5.x) + (v6.x + v7.x));
        a.y += ((v0.y + v1.y) + (v2.y + v3.y)) + ((v4.y + v5.y) + (v6.y + v7.y));
        a.z += ((v0.z + v1.z) + (v2.z + v3.z)) + ((v4.z + v5.z) + (v6.z + v7.z));
        a.w += ((v0.w + v1.w) + (v2.w + v3.w)) + ((v4.w + v5.w) + (v6.w + v7.w));
    }
    for (; j < end; ++j) {                    // tail batch: only its parity enters
        float4 v = sx4[col[j] * 4 + f4];
        a.x += v.x; a.y += v.y; a.z += v.z; a.w += v.w;
    }
    a.x += __shfl_xor(a.x, 4);
    a.y += __shfl_xor(a.y, 4);
    a.z += __shfl_xor(a.z, 4);
    a.w += __shfl_xor(a.w, 4);
    if (!half) {
        float di = dinv[node];
        float4 x0 = ((const float4*)xw0)[node * 4 + f4];
        float4 bb = ((const float4*)b1)[f4];
        float vx = fmaxf(x0.x - di * a.x + bb.x, 0.f);
        float vy = fmaxf(x0.y - di * a.y + bb.y, 0.f);
        float vz = fmaxf(x0.z - di * a.z + bb.z, 0.f);
        float vw = fmaxf(x0.w - di * a.w + bb.w, 0.f);
        ((float4*)h)[node * 4 + f4]  = make_float4(vx, vy, vz, vw);
        ((float4*)sh)[node * 4 + f4] = make_float4(di * vx, di * vy, di * vz, di * vw);
    }
}

// ---- layer-2 gather FUSED with dual matmul + log_softmax (8-lane epilogue) ----
#define HROW 20   // padded row stride (floats)
__global__ void gather2_out(const int* __restrict__ rowptr, const int* __restrict__ col,
                            const float* __restrict__ dinv, const float* __restrict__ sh,
                            const float* __restrict__ h, const float* __restrict__ W2,
                            const float* __restrict__ b2, float* __restrict__ out) {
    __shared__ float sW0[H_HID * C_OUT], sW1[H_HID * C_OUT], sb[C_OUT];
    __shared__ float hrow[64][HROW];    // 5 KB
    __shared__ float trow[64][HROW];    // 5 KB
    for (int i = threadIdx.x; i < H_HID * C_OUT; i += 512) {
        sW0[i] = W2[i];
        sW1[i] = W2[H_HID * C_OUT + i];
    }
    if (threadIdx.x < C_OUT) sb[threadIdx.x] = b2[threadIdx.x];

    int grp  = threadIdx.x >> 2;
    int f4   = threadIdx.x & 3;
    int half = grp & 1;
    int nl   = grp >> 1;                 // 0..63 node-local
    int node = blockIdx.x * 64 + nl;
    bool active = node < N_NODES;
    int beg = 0, end = 0;
    float di = 0.f;
    if (active) { beg = rowptr[node]; end = rowptr[node + 1]; di = dinv[node]; }
    const float4* sh4 = (const float4*)sh;
    float4 a = make_float4(0.f, 0.f, 0.f, 0.f);
    int j = beg + half * 8;
    for (; j + 8 <= end; j += 16) {
        int c0 = col[j],     c1 = col[j + 1], c2 = col[j + 2], c3 = col[j + 3];
        int c4 = col[j + 4], c5 = col[j + 5], c6 = col[j + 6], c7 = col[j + 7];
        float4 v0 = sh4[c0 * 4 + f4], v1 = sh4[c1 * 4 + f4];
        float4 v2 = sh4[c2 * 4 + f4], v3 = sh4[c3 * 4 + f4];
        float4 v4 = sh4[c4 * 4 + f4], v5 = sh4[c5 * 4 + f4];
        float4 v6 = sh4[c6 * 4 + f4], v7 = sh4[c7 * 4 + f4];
        a.x += ((v0.x + v1.x) + (v2.x + v3.x)) + ((v4.x + v5.x) + (v6.x + v7.x));
        a.y += ((v0.y + v1.y) + (v2.y + v3.y)) + ((v4.y + v5.y) + (v6.y + v7.y));
        a.z += ((v0.z + v1.z) + (v2.z + v3.z)) + ((v4.z + v5.z) + (v6.z + v7.z));
        a.w += ((v0.w + v1.w) + (v2.w + v3.w)) + ((v4.w + v5.w) + (v6.w + v7.w));
    }
    for (; j < end; ++j) {
        float4 v = sh4[col[j] * 4 + f4];
        a.x += v.x; a.y += v.y; a.z += v.z; a.w += v.w;
    }
    a.x += __shfl_xor(a.x, 4);
    a.y += __shfl_xor(a.y, 4);
    a.z += __shfl_xor(a.z, 4);
    a.w += __shfl_xor(a.w, 4);
    if (!half) {
        float4 hp = make_float4(0.f, 0.f, 0.f, 0.f);
        if (active) hp = ((const float4*)h)[node * 4 + f4];
        hrow[nl][4 * f4 + 0] = hp.x;
        hrow[nl][4 * f4 + 1] = hp.y;
        hrow[nl][4 * f4 + 2] = hp.z;
        hrow[nl][4 * f4 + 3] = hp.w;
        trow[nl][4 * f4 + 0] = -di * a.x;
        trow[nl][4 * f4 + 1] = -di * a.y;
        trow[nl][4 * f4 + 2] = -di * a.z;
        trow[nl][4 * f4 + 3] = -di * a.w;
    }
    __syncthreads();

    int l8 = threadIdx.x & 7;            // 8 lanes per node, 5 classes each
    float hv[H_HID], tv[H_HID];
    #pragma unroll
    for (int ff = 0; ff < H_HID; ++ff) {
        hv[ff] = hrow[nl][ff];
        tv[ff] = trow[nl][ff];
    }
    float o[5];
    float mx = -1e30f;
    #pragma unroll
    for (int i = 0; i < 5; ++i) {
        int c = l8 * 5 + i;
        float aa = sb[c];
        #pragma unroll
        for (int ff = 0; ff < H_HID; ++ff)
            aa += hv[ff] * sW0[ff * C_OUT + c] + tv[ff] * sW1[ff * C_OUT + c];
        o[i] = aa;
        mx = fmaxf(mx, aa);
    }
    mx = fmaxf(mx, __shfl_xor(mx, 1));
    mx = fmaxf(mx, __shfl_xor(mx, 2));
    mx = fmaxf(mx, __shfl_xor(mx, 4));
    float sum = 0.f;
    #pragma unroll
    for (int i = 0; i < 5; ++i) sum += expf(o[i] - mx);
    sum += __shfl_xor(sum, 1);
    sum += __shfl_xor(sum, 2);
    sum += __shfl_xor(sum, 4);
    float lse = mx + logf(sum);
    if (active) {
        float* op = out + (size_t)node * C_OUT + l8 * 5;
        #pragma unroll
        for (int i = 0; i < 5; ++i) op[i] = o[i] - lse;
    }
}

extern "C" void kernel_launch(void* const* d_in, const int* in_sizes, int n_in,
                              void* d_out, int out_size, void* d_ws, size_t ws_size,
                              hipStream_t stream) {
    const float* x   = (const float*)d_in[0];
    const int*   ei  = (const int*)d_in[1];
    const float* W1  = (const float*)d_in[2];
    const float* b1  = (const float*)d_in[3];
    const float* W2  = (const float*)d_in[4];
    const float* b2  = (const float*)d_in[5];
    float* out = (float*)d_out;

    const int* src = ei;            // edge_index[0]
    const int* dst = ei + N_EDGES;  // edge_index[1]

    // workspace layout
    int* partS = (int*)d_ws;                                      // NBLK*NBUCKP
    int* partD = partS + NBLK * NBUCKP;                           // NBLK*NBUCKP
    int* baseS = partD + NBLK * NBUCKP;                           // NBUCK+1 (pad 512)
    int* baseD = baseS + 512;                                     // NBUCK+1 (pad 512)
    int* totS  = baseD + 512;                                     // NBUCK (pad 512)
    int* totD  = totS + 512;                                      // NBUCK (pad 512)
    unsigned int*  packedD = (unsigned int*)(totD + 512);         // E
    unsigned char* srcloc  = (unsigned char*)(packedD + N_EDGES); // E bytes
    int*   col    = (int*)(srcloc + N_EDGES);                     // E
    int*   rowptr = col + N_EDGES;                                // N+1 (pad)
    float* dinv   = (float*)(rowptr + N_NODES + 8);               // N
    float* xw0    = dinv + N_NODES;                               // N*16
    float* sxw1   = xw0  + (size_t)N_NODES * H_HID;               // N*16
    float* h      = sxw1 + (size_t)N_NODES * H_HID;               // N*16
    float* sh     = h    + (size_t)N_NODES * H_HID;               // N*16

    bucket_count     <<<NBLK, 256, 0, stream>>>(src, dst, partS, partD);
    bucket_base_scan <<<dim3(NBUCK, 2), 512, 0, stream>>>(partS, partD, totS, totD);
    bucket_base_final<<<2, 512, 0, stream>>>(totS, totD, baseS, baseD);
    bucket_scatter   <<<NBLK, 256, 0, stream>>>(src, dst, partS, partD, baseS, baseD, packedD, srcloc);
    csr_build        <<<NBUCK, 512, 0, stream>>>(packedD, baseD, srcloc, baseS, col, rowptr, dinv);
    xw_kernel        <<<N_NODES / 16, 256, 0, stream>>>(x, W1, dinv, xw0, sxw1);
    gather1          <<<(N_NODES + 63) / 64, 512, 0, stream>>>(rowptr, col, dinv, sxw1, xw0, b1, h, sh);
    gather2_out      <<<(N_NODES + 63) / 64, 512, 0, stream>>>(rowptr, col, dinv, sh, h, W2, b2, out);
}

// Round 14
// 90.306 us; speedup vs baseline: 1.8934x; 1.0414x over previous
//
#include <hip/hip_runtime.h>
#include <math.h>

#define N_NODES 50000
#define N_EDGES 800000
#define D_IN    64
#define H_HID   16
#define C_OUT   40

#define BSH     7                                  // 128 nodes per bucket
#define BNODES  128
#define BMASK   127
#define NBUCK   ((N_NODES + BNODES - 1) / BNODES)  // 391
#define NBUCKP  400                                // padded stride for part arrays
#define NBLK    500                                // edge slabs
#define EPB     (N_EDGES / NBLK)                   // 1600 exact, 16B-aligned
#define EPB4    (EPB / 4)                          // 400 int4s per slab

// ---- pass A: per-(block,bucket) histograms, LDS only; part[block][bucket] ----
__global__ void bucket_count(const int* __restrict__ src, const int* __restrict__ dst,
                             int* __restrict__ partS, int* __restrict__ partD) {
    __shared__ int hS[NBUCK], hD[NBUCK];
    for (int i = threadIdx.x; i < NBUCK; i += blockDim.x) { hS[i] = 0; hD[i] = 0; }
    __syncthreads();
    const int4* s4 = (const int4*)(src + blockIdx.x * EPB);
    const int4* d4 = (const int4*)(dst + blockIdx.x * EPB);
    for (int k = threadIdx.x; k < EPB4; k += blockDim.x) {
        int4 s = s4[k], d = d4[k];
        atomicAdd(&hS[s.x >> BSH], 1); atomicAdd(&hS[s.y >> BSH], 1);
        atomicAdd(&hS[s.z >> BSH], 1); atomicAdd(&hS[s.w >> BSH], 1);
        atomicAdd(&hD[d.x >> BSH], 1); atomicAdd(&hD[d.y >> BSH], 1);
        atomicAdd(&hD[d.z >> BSH], 1); atomicAdd(&hD[d.w >> BSH], 1);
    }
    __syncthreads();
    for (int i = threadIdx.x; i < NBUCK; i += blockDim.x) {
        partS[blockIdx.x * NBUCKP + i] = hS[i];
        partD[blockIdx.x * NBUCKP + i] = hD[i];
    }
}

// ---- prefix over blocks, one block per (bucket, S/D): part[k][b] <- sum_{k'<k} ----
__global__ void bucket_base_scan(int* __restrict__ partS, int* __restrict__ partD,
                                 int* __restrict__ totS, int* __restrict__ totD) {
    int* part = blockIdx.y ? partD : partS;
    int* tot  = blockIdx.y ? totD  : totS;
    int b = blockIdx.x;
    __shared__ int s[512];
    int k = threadIdx.x;
    int v = (k < NBLK) ? part[k * NBUCKP + b] : 0;
    s[k] = v;
    __syncthreads();
    for (int off = 1; off < 512; off <<= 1) {
        int t = (k >= off) ? s[k - off] : 0;
        __syncthreads();
        s[k] += t;
        __syncthreads();
    }
    if (k < NBLK) part[k * NBUCKP + b] = s[k] - v;   // exclusive within bucket
    if (k == 511) tot[b] = s[511];
}

// ---- exclusive scan of bucket totals -> base ----
__global__ void bucket_base_final(const int* __restrict__ totS, const int* __restrict__ totD,
                                  int* __restrict__ baseS, int* __restrict__ baseD) {
    const int* tot = blockIdx.x ? totD : totS;
    int* base = blockIdx.x ? baseD : baseS;
    __shared__ int s[512];
    int k = threadIdx.x;
    int v = (k < NBUCK) ? tot[k] : 0;
    s[k] = v;
    __syncthreads();
    for (int off = 1; off < 512; off <<= 1) {
        int t = (k >= off) ? s[k - off] : 0;
        __syncthreads();
        s[k] += t;
        __syncthreads();
    }
    if (k < NBUCK) base[k] = s[k] - v;
    if (k == NBUCK - 1) base[NBUCK] = s[k];   // total == N_EDGES
}

// ---- pass B: scatter edges into bucket-grouped arrays; cursors = 2 coalesced loads ----
__global__ void bucket_scatter(const int* __restrict__ src, const int* __restrict__ dst,
                               const int* __restrict__ partS, const int* __restrict__ partD,
                               const int* __restrict__ baseS, const int* __restrict__ baseD,
                               unsigned int* __restrict__ packedD,
                               unsigned char* __restrict__ srcloc) {
    __shared__ int cS[NBUCK], cD[NBUCK];
    int blk = blockIdx.x;
    for (int b = threadIdx.x; b < NBUCK; b += blockDim.x) {
        cS[b] = baseS[b] + partS[blk * NBUCKP + b];
        cD[b] = baseD[b] + partD[blk * NBUCKP + b];
    }
    __syncthreads();
    const int4* s4 = (const int4*)(src + blk * EPB);
    const int4* d4 = (const int4*)(dst + blk * EPB);
    for (int k = threadIdx.x; k < EPB4; k += blockDim.x) {
        int4 sv = s4[k], dv = d4[k];
        int ss[4] = { sv.x, sv.y, sv.z, sv.w };
        int dd[4] = { dv.x, dv.y, dv.z, dv.w };
        #pragma unroll
        for (int u = 0; u < 4; ++u) {
            int s = ss[u], d = dd[u];
            int pD = atomicAdd(&cD[d >> BSH], 1);
            packedD[pD] = (unsigned)s | ((unsigned)(d & BMASK) << 16);
            int pS = atomicAdd(&cS[s >> BSH], 1);
            srcloc[pS] = (unsigned char)(s & BMASK);
        }
    }
}

// ---- per-bucket counting sort -> per-node CSR (col, rowptr) + src-degree -> dinv ----
__global__ void csr_build(const unsigned int* __restrict__ packedD, const int* __restrict__ baseD,
                          const unsigned char* __restrict__ srcloc, const int* __restrict__ baseS,
                          int* __restrict__ col, int* __restrict__ rowptr,
                          float* __restrict__ dinv) {
    __shared__ int hist[BNODES], scanv[BNODES], cur[BNODES], shist[BNODES];
    int tid = threadIdx.x;
    if (tid < BNODES) { hist[tid] = 0; shist[tid] = 0; }
    __syncthreads();
    int bb = blockIdx.x;
    int begD = baseD[bb], endD = baseD[bb + 1];
    for (int j = begD + tid; j < endD; j += blockDim.x)
        atomicAdd(&hist[(packedD[j] >> 16) & BMASK], 1);
    int begS = baseS[bb], endS = baseS[bb + 1];
    for (int j = begS + tid; j < endS; j += blockDim.x)
        atomicAdd(&shist[srcloc[j]], 1);
    __syncthreads();
    if (tid == 0) {
        int acc = 0;
        for (int i = 0; i < BNODES; ++i) { scanv[i] = acc; acc += hist[i]; }
    }
    __syncthreads();
    if (tid < BNODES) {
        cur[tid] = scanv[tid];
        int node = bb * BNODES + tid;
        if (node < N_NODES) {
            rowptr[node] = begD + scanv[tid];
            int d = shist[tid];
            dinv[node] = (d > 0) ? rsqrtf((float)d) : 0.0f;
        }
    }
    if (bb == NBUCK - 1 && tid == 0) rowptr[N_NODES] = endD;   // == N_EDGES
    __syncthreads();
    for (int j = begD + tid; j < endD; j += blockDim.x) {
        unsigned rec = packedD[j];
        int dl = (rec >> 16) & BMASK;
        int pos = atomicAdd(&cur[dl], 1);
        col[begD + pos] = (int)(rec & 0xFFFF);   // global src id (fits 16b: N<65536)
    }
}

// ---- xw0 = x@W1[0]; sxw1 = dinv * (x@W1[1]) ----
__global__ void xw_kernel(const float* __restrict__ x, const float* __restrict__ W1,
                          const float* __restrict__ dinv,
                          float* __restrict__ xw0, float* __restrict__ sxw1) {
    __shared__ float sW[2 * D_IN * H_HID];   // 8 KB
    __shared__ float sx[16 * 65];
    for (int i = threadIdx.x; i < 2 * D_IN * H_HID; i += 256) sW[i] = W1[i];
    int nbase = blockIdx.x * 16;
    for (int i = threadIdx.x; i < 16 * D_IN; i += 256) {
        int r = i >> 6, c = i & 63;
        sx[r * 65 + c] = x[(size_t)(nbase + r) * D_IN + c];
    }
    __syncthreads();
    int nl = threadIdx.x >> 4, f = threadIdx.x & 15;
    int node = nbase + nl;                    // N = 3125*16 exactly
    float a0 = 0.f, a1 = 0.f;
    #pragma unroll
    for (int d = 0; d < D_IN; ++d) {
        float xv = sx[nl * 65 + d];
        a0 += xv * sW[d * H_HID + f];
        a1 += xv * sW[D_IN * H_HID + d * H_HID + f];
    }
    int t = node * H_HID + f;
    xw0[t]  = a0;
    sxw1[t] = dinv[node] * a1;
}

// 16-deep gather macro body: 16 col loads -> 16 independent float4 gathers in flight
#define GATHER16(TBL)                                                              \
    for (; j + 16 <= end; j += 16) {                                               \
        int cc[16];                                                                \
        _Pragma("unroll")                                                          \
        for (int u = 0; u < 16; ++u) cc[u] = col[j + u];                           \
        float4 vv[16];                                                             \
        _Pragma("unroll")                                                          \
        for (int u = 0; u < 16; ++u) vv[u] = TBL[cc[u] * 4 + f4];                  \
        _Pragma("unroll")                                                          \
        for (int u = 0; u < 16; ++u) {                                             \
            a.x += vv[u].x; a.y += vv[u].y; a.z += vv[u].z; a.w += vv[u].w;        \
        }                                                                          \
    }                                                                              \
    for (; j + 8 <= end; j += 8) {                                                 \
        int cc[8];                                                                 \
        _Pragma("unroll")                                                          \
        for (int u = 0; u < 8; ++u) cc[u] = col[j + u];                            \
        float4 vv[8];                                                              \
        _Pragma("unroll")                                                          \
        for (int u = 0; u < 8; ++u) vv[u] = TBL[cc[u] * 4 + f4];                   \
        _Pragma("unroll")                                                          \
        for (int u = 0; u < 8; ++u) {                                              \
            a.x += vv[u].x; a.y += vv[u].y; a.z += vv[u].z; a.w += vv[u].w;        \
        }                                                                          \
    }                                                                              \
    for (; j < end; ++j) {                                                         \
        float4 v = TBL[col[j] * 4 + f4];                                           \
        a.x += v.x; a.y += v.y; a.z += v.z; a.w += v.w;                            \
    }

// ---- layer-1 gather: 4 lanes per node (float4/lane), 16 nodes/wave, 16-deep unroll ----
__global__ void gather1(const int* __restrict__ rowptr, const int* __restrict__ col,
                        const float* __restrict__ dinv, const float* __restrict__ sxw1,
                        const float* __restrict__ xw0, const float* __restrict__ b1,
                        float* __restrict__ h, float* __restrict__ sh) {
    int grp = threadIdx.x >> 2;               // 128 groups per 512-thread block
    int f4  = threadIdx.x & 3;                // float4 slot (4 feats per lane)
    int node = blockIdx.x * 128 + grp;
    if (node >= N_NODES) return;
    int beg = rowptr[node], end = rowptr[node + 1];
    const float4* sx4 = (const float4*)sxw1;
    float4 a = make_float4(0.f, 0.f, 0.f, 0.f);
    int j = beg;
    GATHER16(sx4)
    float di = dinv[node];
    float4 x0 = ((const float4*)xw0)[node * 4 + f4];
    float4 bb = ((const float4*)b1)[f4];
    float vx = fmaxf(x0.x - di * a.x + bb.x, 0.f);
    float vy = fmaxf(x0.y - di * a.y + bb.y, 0.f);
    float vz = fmaxf(x0.z - di * a.z + bb.z, 0.f);
    float vw = fmaxf(x0.w - di * a.w + bb.w, 0.f);
    ((float4*)h)[node * 4 + f4]  = make_float4(vx, vy, vz, vw);
    ((float4*)sh)[node * 4 + f4] = make_float4(di * vx, di * vy, di * vz, di * vw);
}

// ---- layer-2 gather FUSED with dual matmul + log_softmax (4-lane groups) ----
#define HROW 20   // padded row stride (floats) to break 64B bank aliasing
__global__ void gather2_out(const int* __restrict__ rowptr, const int* __restrict__ col,
                            const float* __restrict__ dinv, const float* __restrict__ sh,
                            const float* __restrict__ h, const float* __restrict__ W2,
                            const float* __restrict__ b2, float* __restrict__ out) {
    __shared__ float sW0[H_HID * C_OUT], sW1[H_HID * C_OUT], sb[C_OUT];
    __shared__ float hrow[128][HROW];    // 10 KB
    __shared__ float trow[128][HROW];    // 10 KB
    for (int i = threadIdx.x; i < H_HID * C_OUT; i += 512) {
        sW0[i] = W2[i];
        sW1[i] = W2[H_HID * C_OUT + i];
    }
    if (threadIdx.x < C_OUT) sb[threadIdx.x] = b2[threadIdx.x];

    int grp = threadIdx.x >> 2;
    int f4  = threadIdx.x & 3;
    int node = blockIdx.x * 128 + grp;
    bool active = node < N_NODES;
    int beg = 0, end = 0;
    float di = 0.f;
    if (active) { beg = rowptr[node]; end = rowptr[node + 1]; di = dinv[node]; }
    const float4* sh4 = (const float4*)sh;
    float4 a = make_float4(0.f, 0.f, 0.f, 0.f);
    int j = beg;
    GATHER16(sh4)
    float4 hp = make_float4(0.f, 0.f, 0.f, 0.f);
    if (active) hp = ((const float4*)h)[node * 4 + f4];
    hrow[grp][4 * f4 + 0] = hp.x;
    hrow[grp][4 * f4 + 1] = hp.y;
    hrow[grp][4 * f4 + 2] = hp.z;
    hrow[grp][4 * f4 + 3] = hp.w;
    trow[grp][4 * f4 + 0] = -di * a.x;
    trow[grp][4 * f4 + 1] = -di * a.y;
    trow[grp][4 * f4 + 2] = -di * a.z;
    trow[grp][4 * f4 + 3] = -di * a.w;
    __syncthreads();

    float hv[H_HID], tv[H_HID];
    #pragma unroll
    for (int ff = 0; ff < H_HID; ++ff) {
        hv[ff] = hrow[grp][ff];
        tv[ff] = trow[grp][ff];
    }
    float o[10];
    float mx = -1e30f;
    #pragma unroll
    for (int i = 0; i < 10; ++i) {
        int c = f4 * 10 + i;
        float aa = sb[c];
        #pragma unroll
        for (int ff = 0; ff < H_HID; ++ff)
            aa += hv[ff] * sW0[ff * C_OUT + c] + tv[ff] * sW1[ff * C_OUT + c];
        o[i] = aa;
        mx = fmaxf(mx, aa);
    }
    mx = fmaxf(mx, __shfl_xor(mx, 1));
    mx = fmaxf(mx, __shfl_xor(mx, 2));
    float sum = 0.f;
    #pragma unroll
    for (int i = 0; i < 10; ++i) sum += expf(o[i] - mx);
    sum += __shfl_xor(sum, 1);
    sum += __shfl_xor(sum, 2);
    float lse = mx + logf(sum);
    if (active) {
        float* op = out + (size_t)node * C_OUT + f4 * 10;
        #pragma unroll
        for (int i = 0; i < 10; ++i) op[i] = o[i] - lse;
    }
}

extern "C" void kernel_launch(void* const* d_in, const int* in_sizes, int n_in,
                              void* d_out, int out_size, void* d_ws, size_t ws_size,
                              hipStream_t stream) {
    const float* x   = (const float*)d_in[0];
    const int*   ei  = (const int*)d_in[1];
    const float* W1  = (const float*)d_in[2];
    const float* b1  = (const float*)d_in[3];
    const float* W2  = (const float*)d_in[4];
    const float* b2  = (const float*)d_in[5];
    float* out = (float*)d_out;

    const int* src = ei;            // edge_index[0]
    const int* dst = ei + N_EDGES;  // edge_index[1]

    // workspace layout
    int* partS = (int*)d_ws;                                      // NBLK*NBUCKP
    int* partD = partS + NBLK * NBUCKP;                           // NBLK*NBUCKP
    int* baseS = partD + NBLK * NBUCKP;                           // NBUCK+1 (pad 512)
    int* baseD = baseS + 512;                                     // NBUCK+1 (pad 512)
    int* totS  = baseD + 512;                                     // NBUCK (pad 512)
    int* totD  = totS + 512;                                      // NBUCK (pad 512)
    unsigned int*  packedD = (unsigned int*)(totD + 512);         // E
    unsigned char* srcloc  = (unsigned char*)(packedD + N_EDGES); // E bytes
    int*   col    = (int*)(srcloc + N_EDGES);                     // E
    int*   rowptr = col + N_EDGES;                                // N+1 (pad)
    float* dinv   = (float*)(rowptr + N_NODES + 8);               // N
    float* xw0    = dinv + N_NODES;                               // N*16
    float* sxw1   = xw0  + (size_t)N_NODES * H_HID;               // N*16
    float* h      = sxw1 + (size_t)N_NODES * H_HID;               // N*16
    float* sh     = h    + (size_t)N_NODES * H_HID;               // N*16

    bucket_count     <<<NBLK, 256, 0, stream>>>(src, dst, partS, partD);
    bucket_base_scan <<<dim3(NBUCK, 2), 512, 0, stream>>>(partS, partD, totS, totD);
    bucket_base_final<<<2, 512, 0, stream>>>(totS, totD, baseS, baseD);
    bucket_scatter   <<<NBLK, 256, 0, stream>>>(src, dst, partS, partD, baseS, baseD, packedD, srcloc);
    csr_build        <<<NBUCK, 512, 0, stream>>>(packedD, baseD, srcloc, baseS, col, rowptr, dinv);
    xw_kernel        <<<N_NODES / 16, 256, 0, stream>>>(x, W1, dinv, xw0, sxw1);
    gather1          <<<(N_NODES + 127) / 128, 512, 0, stream>>>(rowptr, col, dinv, sxw1, xw0, b1, h, sh);
    gather2_out      <<<(N_NODES + 127) / 128, 512, 0, stream>>>(rowptr, col, dinv, sh, h, W2, b2, out);
}

// Round 15
// 83.013 us; speedup vs baseline: 2.0598x; 1.0879x over previous
//
#include <hip/hip_runtime.h>
#include <hip/hip_fp16.h>
#include <math.h>

#define N_NODES 50000
#define N_EDGES 800000
#define D_IN    64
#define H_HID   16
#define C_OUT   40

#define BSH     7                                  // 128 nodes per bucket
#define BNODES  128
#define BMASK   127
#define NBUCK   ((N_NODES + BNODES - 1) / BNODES)  // 391
#define NBUCKP  400                                // padded stride for part arrays
#define NBLK    500                                // edge slabs
#define EPB     (N_EDGES / NBLK)                   // 1600 exact, 16B-aligned
#define EPB4    (EPB / 4)                          // 400 int4s per slab

// ---- pass A: per-(block,bucket) histograms, LDS only; part[block][bucket] ----
__global__ void bucket_count(const int* __restrict__ src, const int* __restrict__ dst,
                             int* __restrict__ partS, int* __restrict__ partD) {
    __shared__ int hS[NBUCK], hD[NBUCK];
    for (int i = threadIdx.x; i < NBUCK; i += blockDim.x) { hS[i] = 0; hD[i] = 0; }
    __syncthreads();
    const int4* s4 = (const int4*)(src + blockIdx.x * EPB);
    const int4* d4 = (const int4*)(dst + blockIdx.x * EPB);
    for (int k = threadIdx.x; k < EPB4; k += blockDim.x) {
        int4 s = s4[k], d = d4[k];
        atomicAdd(&hS[s.x >> BSH], 1); atomicAdd(&hS[s.y >> BSH], 1);
        atomicAdd(&hS[s.z >> BSH], 1); atomicAdd(&hS[s.w >> BSH], 1);
        atomicAdd(&hD[d.x >> BSH], 1); atomicAdd(&hD[d.y >> BSH], 1);
        atomicAdd(&hD[d.z >> BSH], 1); atomicAdd(&hD[d.w >> BSH], 1);
    }
    __syncthreads();
    for (int i = threadIdx.x; i < NBUCK; i += blockDim.x) {
        partS[blockIdx.x * NBUCKP + i] = hS[i];
        partD[blockIdx.x * NBUCKP + i] = hD[i];
    }
}

// ---- prefix over blocks, one block per (bucket, S/D): part[k][b] <- sum_{k'<k} ----
__global__ void bucket_base_scan(int* __restrict__ partS, int* __restrict__ partD,
                                 int* __restrict__ totS, int* __restrict__ totD) {
    int* part = blockIdx.y ? partD : partS;
    int* tot  = blockIdx.y ? totD  : totS;
    int b = blockIdx.x;
    __shared__ int s[512];
    int k = threadIdx.x;
    int v = (k < NBLK) ? part[k * NBUCKP + b] : 0;
    s[k] = v;
    __syncthreads();
    for (int off = 1; off < 512; off <<= 1) {
        int t = (k >= off) ? s[k - off] : 0;
        __syncthreads();
        s[k] += t;
        __syncthreads();
    }
    if (k < NBLK) part[k * NBUCKP + b] = s[k] - v;   // exclusive within bucket
    if (k == 511) tot[b] = s[511];
}

// ---- exclusive scan of bucket totals -> base ----
__global__ void bucket_base_final(const int* __restrict__ totS, const int* __restrict__ totD,
                                  int* __restrict__ baseS, int* __restrict__ baseD) {
    const int* tot = blockIdx.x ? totD : totS;
    int* base = blockIdx.x ? baseD : baseS;
    __shared__ int s[512];
    int k = threadIdx.x;
    int v = (k < NBUCK) ? tot[k] : 0;
    s[k] = v;
    __syncthreads();
    for (int off = 1; off < 512; off <<= 1) {
        int t = (k >= off) ? s[k - off] : 0;
        __syncthreads();
        s[k] += t;
        __syncthreads();
    }
    if (k < NBUCK) base[k] = s[k] - v;
    if (k == NBUCK - 1) base[NBUCK] = s[k];   // total == N_EDGES
}

// ---- pass B: scatter edges into bucket-grouped arrays; cursors = 2 coalesced loads ----
__global__ void bucket_scatter(const int* __restrict__ src, const int* __restrict__ dst,
                               const int* __restrict__ partS, const int* __restrict__ partD,
                               const int* __restrict__ baseS, const int* __restrict__ baseD,
                               unsigned int* __restrict__ packedD,
                               unsigned char* __restrict__ srcloc) {
    __shared__ int cS[NBUCK], cD[NBUCK];
    int blk = blockIdx.x;
    for (int b = threadIdx.x; b < NBUCK; b += blockDim.x) {
        cS[b] = baseS[b] + partS[blk * NBUCKP + b];
        cD[b] = baseD[b] + partD[blk * NBUCKP + b];
    }
    __syncthreads();
    const int4* s4 = (const int4*)(src + blk * EPB);
    const int4* d4 = (const int4*)(dst + blk * EPB);
    for (int k = threadIdx.x; k < EPB4; k += blockDim.x) {
        int4 sv = s4[k], dv = d4[k];
        int ss[4] = { sv.x, sv.y, sv.z, sv.w };
        int dd[4] = { dv.x, dv.y, dv.z, dv.w };
        #pragma unroll
        for (int u = 0; u < 4; ++u) {
            int s = ss[u], d = dd[u];
            int pD = atomicAdd(&cD[d >> BSH], 1);
            packedD[pD] = (unsigned)s | ((unsigned)(d & BMASK) << 16);
            int pS = atomicAdd(&cS[s >> BSH], 1);
            srcloc[pS] = (unsigned char)(s & BMASK);
        }
    }
}

// ---- per-bucket counting sort -> per-node CSR (ushort col, rowptr) + dinv ----
__global__ void csr_build(const unsigned int* __restrict__ packedD, const int* __restrict__ baseD,
                          const unsigned char* __restrict__ srcloc, const int* __restrict__ baseS,
                          unsigned short* __restrict__ col, int* __restrict__ rowptr,
                          float* __restrict__ dinv) {
    __shared__ int hist[BNODES], scanv[BNODES], cur[BNODES], shist[BNODES];
    int tid = threadIdx.x;
    if (tid < BNODES) { hist[tid] = 0; shist[tid] = 0; }
    __syncthreads();
    int bb = blockIdx.x;
    int begD = baseD[bb], endD = baseD[bb + 1];
    for (int j = begD + tid; j < endD; j += blockDim.x)
        atomicAdd(&hist[(packedD[j] >> 16) & BMASK], 1);
    int begS = baseS[bb], endS = baseS[bb + 1];
    for (int j = begS + tid; j < endS; j += blockDim.x)
        atomicAdd(&shist[srcloc[j]], 1);
    __syncthreads();
    if (tid == 0) {
        int acc = 0;
        for (int i = 0; i < BNODES; ++i) { scanv[i] = acc; acc += hist[i]; }
    }
    __syncthreads();
    if (tid < BNODES) {
        cur[tid] = scanv[tid];
        int node = bb * BNODES + tid;
        if (node < N_NODES) {
            rowptr[node] = begD + scanv[tid];
            int d = shist[tid];
            dinv[node] = (d > 0) ? rsqrtf((float)d) : 0.0f;
        }
    }
    if (bb == NBUCK - 1 && tid == 0) rowptr[N_NODES] = endD;   // == N_EDGES
    __syncthreads();
    for (int j = begD + tid; j < endD; j += blockDim.x) {
        unsigned rec = packedD[j];
        int dl = (rec >> 16) & BMASK;
        int pos = atomicAdd(&cur[dl], 1);
        col[begD + pos] = (unsigned short)(rec & 0xFFFF);   // src id fits 16b (N<65536)
    }
}

// ---- xw0 = x@W1[0] (fp32); sxw1 = dinv * (x@W1[1]) stored as fp16 ----
__global__ void xw_kernel(const float* __restrict__ x, const float* __restrict__ W1,
                          const float* __restrict__ dinv,
                          float* __restrict__ xw0, __half* __restrict__ sxw1h) {
    __shared__ float sW[2 * D_IN * H_HID];   // 8 KB
    __shared__ float sx[16 * 65];
    for (int i = threadIdx.x; i < 2 * D_IN * H_HID; i += 256) sW[i] = W1[i];
    int nbase = blockIdx.x * 16;
    for (int i = threadIdx.x; i < 16 * D_IN; i += 256) {
        int r = i >> 6, c = i & 63;
        sx[r * 65 + c] = x[(size_t)(nbase + r) * D_IN + c];
    }
    __syncthreads();
    int nl = threadIdx.x >> 4, f = threadIdx.x & 15;
    int node = nbase + nl;                    // N = 3125*16 exactly
    float a0 = 0.f, a1 = 0.f;
    #pragma unroll
    for (int d = 0; d < D_IN; ++d) {
        float xv = sx[nl * 65 + d];
        a0 += xv * sW[d * H_HID + f];
        a1 += xv * sW[D_IN * H_HID + d * H_HID + f];
    }
    int t = node * H_HID + f;
    xw0[t]   = a0;
    sxw1h[t] = __float2half_rn(dinv[node] * a1);
}

// unpack uint2 (4 halves) and accumulate into 4 fp32 accumulators
#define ACC4(V)                                                       \
    {                                                                 \
        __half2 p0 = *reinterpret_cast<const __half2*>(&(V).x);       \
        __half2 p1 = *reinterpret_cast<const __half2*>(&(V).y);       \
        float2 f0 = __half22float2(p0), f1 = __half22float2(p1);      \
        a0 += f0.x; a1 += f0.y; a2 += f1.x; a3 += f1.y;               \
    }

// 16/8/1-deep gather over fp16 table (uint2 = 4 halves per lane)
#define GATHERH(TBL)                                                  \
    for (; j + 16 <= end; j += 16) {                                  \
        int cc[16];                                                   \
        _Pragma("unroll")                                             \
        for (int u = 0; u < 16; ++u) cc[u] = col[j + u];              \
        uint2 vv[16];                                                 \
        _Pragma("unroll")                                             \
        for (int u = 0; u < 16; ++u) vv[u] = TBL[cc[u] * 4 + f4];     \
        _Pragma("unroll")                                             \
        for (int u = 0; u < 16; ++u) ACC4(vv[u])                      \
    }                                                                 \
    for (; j + 8 <= end; j += 8) {                                    \
        int cc[8];                                                    \
        _Pragma("unroll")                                             \
        for (int u = 0; u < 8; ++u) cc[u] = col[j + u];               \
        uint2 vv[8];                                                  \
        _Pragma("unroll")                                             \
        for (int u = 0; u < 8; ++u) vv[u] = TBL[cc[u] * 4 + f4];      \
        _Pragma("unroll")                                             \
        for (int u = 0; u < 8; ++u) ACC4(vv[u])                       \
    }                                                                 \
    for (; j < end; ++j) {                                            \
        uint2 v = TBL[col[j] * 4 + f4];                               \
        ACC4(v)                                                       \
    }

// ---- layer-1 gather: 4 lanes/node, fp16 table, 64 nodes per 256-thread block ----
__global__ void gather1(const int* __restrict__ rowptr, const unsigned short* __restrict__ col,
                        const float* __restrict__ dinv, const uint2* __restrict__ sxw1h,
                        const float* __restrict__ xw0, const float* __restrict__ b1,
                        uint2* __restrict__ h16, uint2* __restrict__ sh16) {
    int grp = threadIdx.x >> 2;               // 64 groups per 256-thread block
    int f4  = threadIdx.x & 3;
    int node = blockIdx.x * 64 + grp;
    if (node >= N_NODES) return;
    int beg = rowptr[node], end = rowptr[node + 1];
    float a0 = 0.f, a1 = 0.f, a2 = 0.f, a3 = 0.f;
    int j = beg;
    GATHERH(sxw1h)
    float di = dinv[node];
    float4 x0 = ((const float4*)xw0)[node * 4 + f4];
    float4 bb = ((const float4*)b1)[f4];
    float v0 = fmaxf(x0.x - di * a0 + bb.x, 0.f);
    float v1 = fmaxf(x0.y - di * a1 + bb.y, 0.f);
    float v2 = fmaxf(x0.z - di * a2 + bb.z, 0.f);
    float v3 = fmaxf(x0.w - di * a3 + bb.w, 0.f);
    uint2 hw, sw;
    *reinterpret_cast<__half2*>(&hw.x) = __float22half2_rn(make_float2(v0, v1));
    *reinterpret_cast<__half2*>(&hw.y) = __float22half2_rn(make_float2(v2, v3));
    *reinterpret_cast<__half2*>(&sw.x) = __float22half2_rn(make_float2(di * v0, di * v1));
    *reinterpret_cast<__half2*>(&sw.y) = __float22half2_rn(make_float2(di * v2, di * v3));
    h16[node * 4 + f4]  = hw;
    sh16[node * 4 + f4] = sw;
}

// ---- layer-2 gather FUSED with dual matmul + log_softmax ----
#define HROW 20   // padded LDS row stride
__global__ void gather2_out(const int* __restrict__ rowptr, const unsigned short* __restrict__ col,
                            const float* __restrict__ dinv, const uint2* __restrict__ sh16,
                            const uint2* __restrict__ h16, const float* __restrict__ W2,
                            const float* __restrict__ b2, float* __restrict__ out) {
    __shared__ float sW0[H_HID * C_OUT], sW1[H_HID * C_OUT], sb[C_OUT];
    __shared__ float hrow[64][HROW];    // 5 KB
    __shared__ float trow[64][HROW];    // 5 KB
    for (int i = threadIdx.x; i < H_HID * C_OUT; i += 256) {
        sW0[i] = W2[i];
        sW1[i] = W2[H_HID * C_OUT + i];
    }
    if (threadIdx.x < C_OUT) sb[threadIdx.x] = b2[threadIdx.x];

    int grp = threadIdx.x >> 2;
    int f4  = threadIdx.x & 3;
    int node = blockIdx.x * 64 + grp;
    bool active = node < N_NODES;
    int beg = 0, end = 0;
    float di = 0.f;
    if (active) { beg = rowptr[node]; end = rowptr[node + 1]; di = dinv[node]; }
    float a0 = 0.f, a1 = 0.f, a2 = 0.f, a3 = 0.f;
    int j = beg;
    GATHERH(sh16)
    // stage h row (unpacked) and t1 row into LDS
    float h0 = 0.f, h1 = 0.f, h2 = 0.f, h3 = 0.f;
    if (active) {
        uint2 hv2 = h16[node * 4 + f4];
        __half2 p0 = *reinterpret_cast<const __half2*>(&hv2.x);
        __half2 p1 = *reinterpret_cast<const __half2*>(&hv2.y);
        float2 f0 = __half22float2(p0), f1 = __half22float2(p1);
        h0 = f0.x; h1 = f0.y; h2 = f1.x; h3 = f1.y;
    }
    hrow[grp][4 * f4 + 0] = h0;
    hrow[grp][4 * f4 + 1] = h1;
    hrow[grp][4 * f4 + 2] = h2;
    hrow[grp][4 * f4 + 3] = h3;
    trow[grp][4 * f4 + 0] = -di * a0;
    trow[grp][4 * f4 + 1] = -di * a1;
    trow[grp][4 * f4 + 2] = -di * a2;
    trow[grp][4 * f4 + 3] = -di * a3;
    __syncthreads();

    float hv[H_HID], tv[H_HID];
    #pragma unroll
    for (int ff = 0; ff < H_HID; ++ff) {
        hv[ff] = hrow[grp][ff];
        tv[ff] = trow[grp][ff];
    }
    float o[10];
    float mx = -1e30f;
    #pragma unroll
    for (int i = 0; i < 10; ++i) {
        int c = f4 * 10 + i;
        float aa = sb[c];
        #pragma unroll
        for (int ff = 0; ff < H_HID; ++ff)
            aa += hv[ff] * sW0[ff * C_OUT + c] + tv[ff] * sW1[ff * C_OUT + c];
        o[i] = aa;
        mx = fmaxf(mx, aa);
    }
    mx = fmaxf(mx, __shfl_xor(mx, 1));
    mx = fmaxf(mx, __shfl_xor(mx, 2));
    float sum = 0.f;
    #pragma unroll
    for (int i = 0; i < 10; ++i) sum += expf(o[i] - mx);
    sum += __shfl_xor(sum, 1);
    sum += __shfl_xor(sum, 2);
    float lse = mx + logf(sum);
    if (active) {
        float* op = out + (size_t)node * C_OUT + f4 * 10;
        #pragma unroll
        for (int i = 0; i < 10; ++i) op[i] = o[i] - lse;
    }
}

extern "C" void kernel_launch(void* const* d_in, const int* in_sizes, int n_in,
                              void* d_out, int out_size, void* d_ws, size_t ws_size,
                              hipStream_t stream) {
    const float* x   = (const float*)d_in[0];
    const int*   ei  = (const int*)d_in[1];
    const float* W1  = (const float*)d_in[2];
    const float* b1  = (const float*)d_in[3];
    const float* W2  = (const float*)d_in[4];
    const float* b2  = (const float*)d_in[5];
    float* out = (float*)d_out;

    const int* src = ei;            // edge_index[0]
    const int* dst = ei + N_EDGES;  // edge_index[1]

    // workspace layout
    int* partS = (int*)d_ws;                                      // NBLK*NBUCKP
    int* partD = partS + NBLK * NBUCKP;                           // NBLK*NBUCKP
    int* baseS = partD + NBLK * NBUCKP;                           // NBUCK+1 (pad 512)
    int* baseD = baseS + 512;                                     // NBUCK+1 (pad 512)
    int* totS  = baseD + 512;                                     // NBUCK (pad 512)
    int* totD  = totS + 512;                                      // NBUCK (pad 512)
    unsigned int*   packedD = (unsigned int*)(totD + 512);        // E
    unsigned char*  srcloc  = (unsigned char*)(packedD + N_EDGES);// E bytes
    unsigned short* col     = (unsigned short*)(srcloc + N_EDGES);// E ushorts (E even)
    int*   rowptr = (int*)(col + N_EDGES);                        // N+1 (pad 8)
    float* dinv   = (float*)(rowptr + N_NODES + 8);               // N
    float* xw0    = dinv + N_NODES;                               // N*16 fp32
    __half* sxw1h = (__half*)(xw0 + (size_t)N_NODES * H_HID);     // N*16 fp16
    __half* h16   = sxw1h + (size_t)N_NODES * H_HID;              // N*16 fp16
    __half* sh16  = h16   + (size_t)N_NODES * H_HID;              // N*16 fp16

    bucket_count     <<<NBLK, 256, 0, stream>>>(src, dst, partS, partD);
    bucket_base_scan <<<dim3(NBUCK, 2), 512, 0, stream>>>(partS, partD, totS, totD);
    bucket_base_final<<<2, 512, 0, stream>>>(totS, totD, baseS, baseD);
    bucket_scatter   <<<NBLK, 256, 0, stream>>>(src, dst, partS, partD, baseS, baseD, packedD, srcloc);
    csr_build        <<<NBUCK, 512, 0, stream>>>(packedD, baseD, srcloc, baseS, col, rowptr, dinv);
    xw_kernel        <<<N_NODES / 16, 256, 0, stream>>>(x, W1, dinv, xw0, sxw1h);
    gather1          <<<(N_NODES + 63) / 64, 256, 0, stream>>>(rowptr, col, dinv, (const uint2*)sxw1h,
                                                               xw0, b1, (uint2*)h16, (uint2*)sh16);
    gather2_out      <<<(N_NODES + 63) / 64, 256, 0, stream>>>(rowptr, col, dinv, (const uint2*)sh16,
                                                               (const uint2*)h16, W2, b2, out);
}